// Round 13
// baseline (156.864 us; speedup 1.0000x reference)
//
#include <hip/hip_runtime.h>
#include <hip/hip_bf16.h>

// Problem constants
constexpr int Dd = 1024;           // feature dim
constexpr int Tt = 2048;           // sequence length
constexpr int Bb = 4;              // batch
constexpr int Rr = Bb * Tt;        // rows = 8192
constexpr int RSN = 1032;          // ring entries per shifted copy (1024 + pad)
constexpr int BM  = 64;            // tile rows
constexpr int BN  = 128;           // tile cols
constexpr int BK  = 64;            // K step
constexpr int NST = Dd / BK;       // 16 K-steps
constexpr int NPAN = Rr / BM;      // 128 row-panels

typedef __attribute__((ext_vector_type(2))) float f32x2;
typedef __attribute__((ext_vector_type(16))) float f32x16;
typedef __attribute__((ext_vector_type(8))) short bf16x8;

__device__ __forceinline__ float sigmoidf_(float v) {
    return 1.0f / (1.0f + expf(-v));
}

// ---------------------------------------------------------------------------
// Kernel 1: blocks 0..63: circulant c[n] = sum_m unbind[m]*bind[(m+n)%D].
// blocks 64..317: warmup seg-sums (8-row segs) for 64-row panels 1..127:
//   Sw[p][j][col] = sum_{i=0..7} d^(7-i) x[p*64-32+8j+i][col],  j=0..3
// (batch-start panels produce garbage here; masked by wldz.)
__global__ void k_c(const float* __restrict__ bind,
                    const float* __restrict__ unbind,
                    const float* __restrict__ x,
                    const float* __restrict__ decay,
                    float* __restrict__ c,
                    float* __restrict__ Sw) {
    const int tid = threadIdx.x;
    if (blockIdx.x < 64) {
        __shared__ float sb[Dd];
        __shared__ float su[Dd];
        __shared__ float sp[256];
        for (int j = tid; j < Dd; j += 256) { sb[j] = bind[j]; su[j] = unbind[j]; }
        __syncthreads();
        const int n_loc = tid >> 4;
        const int seg = tid & 15;
        const int n = (int)blockIdx.x * 16 + n_loc;
        float acc = 0.f;
        #pragma unroll 8
        for (int i = 0; i < 64; ++i) {
            const int m = i * 16 + seg;
            acc = fmaf(su[m], sb[(m + n) & (Dd - 1)], acc);
        }
        sp[tid] = acc;
        __syncthreads();
        if (tid < 16) {
            float s = 0.f;
            #pragma unroll
            for (int j = 0; j < 16; ++j) s += sp[tid * 16 + j];
            c[(int)blockIdx.x * 16 + tid] = s;
        }
    } else {
        const int w = (int)blockIdx.x - 64;   // 0..253
        const int p = (w >> 1) + 1;           // panel 1..127
        const int h = w & 1;
        const float dd = sigmoidf_(decay[0]);
        const int col = h * 512 + tid * 2;
        const float* xp = x + (size_t)(p * BM - 32) * Dd + col;
        #pragma unroll
        for (int j = 0; j < 4; ++j) {
            f32x2 sj = (f32x2){0.f, 0.f};
            #pragma unroll
            for (int i = 0; i < 8; ++i)
                sj = dd * sj + *(const f32x2*)&xp[(size_t)(j * 8 + i) * Dd];
            *(f32x2*)&Sw[((size_t)p * 4 + j) * Dd + col] = sj;
        }
    }
}

// ---------------------------------------------------------------------------
// Kernel 2 (fused): out = x + g * (scan_d(x) @ Wt^T), Wt circulant from c.
// R13: same algebra, re-parameterized for OCCUPANCY.  Every prior config had
// 8 waves/CU = 2 waves/SIMD (R6 1x8, R9 2x4, R12 4x2) -- the SIMDs never had
// enough waves to hide the barrier/chain latency (counters: ~19% occ, <30%
// combined util).  Now: BM=64 with 256 threads (4 waves), grid 1024 ->
// 4 blocks/CU x 4 waves = 16 waves/CU = 4 waves/SIMD.  LDS 35.1 KB.
//  * scan: 8 segs x 8 rows; chains = 7 FMAs; carries from 4 predecessor
//    sums C = S[s-1] + d8 S[s-2] + d16 S[s-3] + d24 S[s-4] (trunc d^33,
//    same bound as the verified d^32 horizon).  Sw = [p][4][D].
//  * MFMA: 4 waves x (64 rows x 32-col n-slice); acc 2x f32x16 = 32 regs.
//  * rings, XOR chunk swizzle, C/D layout, 2-deep prefetch: unchanged.
// grid 1024 x 256
__global__ __launch_bounds__(256, 4) void k_fused(
    const float* __restrict__ x,     // [R][D] fp32
    const float* __restrict__ c,     // [D] fp32 circulant kernel
    const float* __restrict__ Sw,    // [128][4][D] warmup seg sums
    const float* __restrict__ decay, // [1]
    const float* __restrict__ gate,  // [1]
    float* __restrict__ out)         // [R][D] fp32
{
    __shared__ __align__(16) __hip_bfloat16 sA[2][BM * BK];  // 2 x 8 KB
    __shared__ __align__(16) __hip_bfloat16 rs[8][RSN];      // 16.1 KB
    __shared__ float sS[12][BK];                             // 3 KB seg sums

    const int tid = threadIdx.x;
    const int wave = tid >> 6;       // 0..3
    const int lane = tid & 63;

    // XCD-grouped mapping: id = xcd + 8*(in_ + 8*gg), bijective over 1024.
    const int id  = blockIdx.x;      // 0..1023
    const int xcd = id & 7;
    const int rr  = id >> 3;         // 0..127
    const int in_ = rr & 7;          // 0..7   col-tile index
    const int gg  = rr >> 3;         // 0..15
    const int im  = xcd * 16 + gg;   // 0..127 row-panel index
    const int tile_m = im * BM;
    const int tile_n = in_ * BN;
    const int pw  = im & 31;         // panel within its batch (2048/64=32)

    const int phase = ((in_ & 1) << 3) | ((gg & 1) << 2);
#define P(T) (((T) + phase) & 15)

    const float dd = sigmoidf_(decay[0]);
    const float d2 = dd * dd, d4 = d2 * d2, d8 = d4 * d4;
    const float d16 = d8 * d8, d24 = d16 * d8;

    // build 8 shifted reversed rings from global c (L2-hot, 4 KB):
    // rs[s][t] = bf16(c[(-(t+s)) mod D])
    #pragma unroll
    for (int s = 0; s < 8; ++s)
        for (int t = tid; t < RSN; t += 256)
            rs[s][t] = __float2bfloat16(c[(-(t + s)) & (Dd - 1)]);

    // ---- scan decomposition: cp = col-pair 0..31, s = seg 0..7 (8 rows) ----
    const int cp = tid & 31;
    const int s  = tid >> 5;         // 0..7
    const bool wldz = (pw == 0);     // first panel in batch: no warmup

    f32x2 vmA[8], vmB[8];            // 2-deep strip prefetch buffers
    f32x2 swA = (f32x2){0.f, 0.f}, swB = (f32x2){0.f, 0.f};

#define LOADSTRIP(V, SWR, ST) do {                                          \
    const int col_ = (ST) * BK + 2 * cp;                                    \
    const float* xp_ = x + (size_t)(tile_m + s * 8) * Dd + col_;            \
    _Pragma("unroll")                                                       \
    for (int i_ = 0; i_ < 8; ++i_)                                          \
        V[i_] = *(const f32x2*)&xp_[(size_t)i_ * Dd];                       \
    if (s >= 4 && !wldz)                                                    \
        SWR = *(const f32x2*)&Sw[((size_t)im * 4 + (s - 4)) * Dd + col_];   \
} while (0)

#define CHAINS(V, SWR) do {                                                 \
    _Pragma("unroll")                                                       \
    for (int i_ = 1; i_ < 8; ++i_) V[i_] = dd * V[i_ - 1] + V[i_];          \
    *(f32x2*)&sS[s][2 * cp] = V[7];                                         \
    if (s >= 4)                                                             \
        *(f32x2*)&sS[8 + (s - 4)][2 * cp] =                                 \
            wldz ? (f32x2){0.f, 0.f} : SWR;                                 \
} while (0)

    // sS[8+j] = Sw[p][j]: j=3 -> rows -8..-1 (S[-1]), j=2 -> S[-2], etc.
    auto loadS = [&](int r) -> f32x2 {
        if (r >= 0) return *(const f32x2*)&sS[r][2 * cp];
        return *(const f32x2*)&sS[12 + r][2 * cp];   // r=-1 -> 11 ... r=-4 -> 8
    };

#define FINISH(V, BB) do {                                                  \
    f32x2 C_ = loadS(s - 1) + d8 * loadS(s - 2)                             \
             + d16 * loadS(s - 3) + d24 * loadS(s - 4);                     \
    float w_ = dd;                                                          \
    _Pragma("unroll")                                                       \
    for (int i_ = 0; i_ < 8; ++i_) {                                        \
        f32x2 h_ = V[i_] + w_ * C_;                                         \
        w_ *= dd;                                                           \
        const int rl_ = s * 8 + i_;                                         \
        const int pos_ = (((2 * cp) >> 3) ^ (rl_ & 7)) * 8 + ((2 * cp) & 7);\
        union { __hip_bfloat16 b; unsigned short u; } ux_, uy_;             \
        ux_.b = __float2bfloat16(h_[0]);                                    \
        uy_.b = __float2bfloat16(h_[1]);                                    \
        ushort2 o_; o_.x = ux_.u; o_.y = uy_.u;                             \
        *(ushort2*)&sA[BB][rl_ * 64 + pos_] = o_;                           \
    }                                                                       \
} while (0)

    // ---- MFMA geometry: 4 waves, each 64 rows x 32-col n-slice ----
    const int wn  = wave * 32;
    const int fm  = lane & 31;
    const int fsw = fm & 7;
    const int fc0 = lane >> 5;
    const int ng0 = tile_n + wn + fm;

    f32x16 acc[2];
    #pragma unroll
    for (int i = 0; i < 2; ++i)
        #pragma unroll
        for (int e = 0; e < 16; ++e)
            acc[i][e] = 0.f;

#define MF(BB, K0) do {                                                     \
    _Pragma("unroll")                                                       \
    for (int kh_ = 0; kh_ < 4; ++kh_) {                                     \
        const int kc_ = kh_ * 2 + fc0;                                      \
        const int ck_ = (K0) + kc_ * 8;                                     \
        bf16x8 af0_ = *(const bf16x8*)                                      \
            &sA[BB][(fm) * 64 + (kc_ ^ fsw) * 8];                           \
        bf16x8 af1_ = *(const bf16x8*)                                      \
            &sA[BB][(32 + fm) * 64 + (kc_ ^ fsw) * 8];                      \
        const int bi0_ = (ck_ - ng0) & (Dd - 1);                            \
        bf16x8 bf0_ = *(const bf16x8*)&rs[bi0_ & 7][bi0_ & ~7];             \
        acc[0] = __builtin_amdgcn_mfma_f32_32x32x16_bf16(                   \
            af0_, bf0_, acc[0], 0, 0, 0);                                   \
        acc[1] = __builtin_amdgcn_mfma_f32_32x32x16_bf16(                   \
            af1_, bf0_, acc[1], 0, 0, 0);                                   \
    }                                                                       \
} while (0)

    // prologue: strips P(0), P(1) issued; strip P(0) -> sA[0]
    LOADSTRIP(vmA, swA, P(0));
    LOADSTRIP(vmB, swB, P(1));
    CHAINS(vmA, swA);
    __syncthreads();              // sS ready (and ring build done)
    FINISH(vmA, 0);
    __syncthreads();              // sA[0] ready

    for (int st = 0; st < NST; st += 2) {
        // even step: MFMA strip P(st) (sA[0]); finish strip P(st+1) -> sA[1]
        if (st + 2 < NST) LOADSTRIP(vmA, swA, P(st + 2));
        MF(0, P(st) * BK);
        CHAINS(vmB, swB);         // strip P(st+1) (loads issued 1 step ago)
        __syncthreads();          // sS visible; sA[0] MFMA reads done
        FINISH(vmB, 1);
        __syncthreads();          // sA[1] ready
        // odd step: MFMA strip P(st+1) (sA[1]); finish P(st+2) -> sA[0]
        if (st + 3 < NST) LOADSTRIP(vmB, swB, P(st + 3));
        MF(1, P(st + 1) * BK);
        if (st + 2 < NST) {
            CHAINS(vmA, swA);     // strip P(st+2)
            __syncthreads();
            FINISH(vmA, 0);
        }
        __syncthreads();
    }

#undef LOADSTRIP
#undef CHAINS
#undef FINISH
#undef MF
#undef P

    // C/D layout (R7-verified): col = lane&31, row = (reg&3)+8*(reg>>2)+4*(lane>>5)
    const float g = gate[0];
    const int colg = tile_n + wn + (lane & 31);
    #pragma unroll
    for (int sm = 0; sm < 2; ++sm) {
        #pragma unroll
        for (int g1 = 0; g1 < 4; ++g1) {
            const int row0 = tile_m + sm * 32 + g1 * 8 + (lane >> 5) * 4;
            #pragma unroll
            for (int r0 = 0; r0 < 4; ++r0) {
                const size_t off = (size_t)(row0 + r0) * Dd + colg;
                out[off] = fmaf(g, acc[sm][g1 * 4 + r0], x[off]);
            }
        }
    }
}

// ---------------------------------------------------------------------------
extern "C" void kernel_launch(void* const* d_in, const int* in_sizes, int n_in,
                              void* d_out, int out_size, void* d_ws, size_t ws_size,
                              hipStream_t stream) {
    const float* x      = (const float*)d_in[0];
    const float* bind   = (const float*)d_in[1];
    const float* unbind = (const float*)d_in[2];
    const float* gate   = (const float*)d_in[3];
    const float* decay  = (const float*)d_in[4];
    float* out = (float*)d_out;

    // workspace: c (4 KB) + Sw (2 MB: 128 panels x 4 x 1024 f32)
    float* c  = (float*)d_ws;
    float* Sw = (float*)((char*)d_ws + 4096);

    k_c    <<<dim3(64 + 2 * (NPAN - 1)), dim3(256), 0, stream>>>(
        bind, unbind, x, decay, c, Sw);
    k_fused<<<dim3(1024), dim3(256), 0, stream>>>(x, c, Sw, decay, gate, out);
}

// Round 14
// 130.593 us; speedup vs baseline: 1.2012x; 1.2012x over previous
//
#include <hip/hip_runtime.h>
#include <hip/hip_bf16.h>

// Problem constants
constexpr int Dd = 1024;           // feature dim
constexpr int Tt = 2048;           // sequence length
constexpr int Bb = 4;              // batch
constexpr int Rr = Bb * Tt;        // rows = 8192
constexpr int RSN = 1032;          // ring entries per shifted copy (1024 + pad)
constexpr int BM  = 64;            // tile rows
constexpr int BN  = 128;           // tile cols
constexpr int BK  = 64;            // K step
constexpr int NST = Dd / BK;       // 16 K-steps
constexpr int NPAN = Rr / BM;      // 128 row-panels

typedef __attribute__((ext_vector_type(2))) float f32x2;
typedef __attribute__((ext_vector_type(16))) float f32x16;
typedef __attribute__((ext_vector_type(8))) short bf16x8;

__device__ __forceinline__ float sigmoidf_(float v) {
    return 1.0f / (1.0f + expf(-v));
}

// ---------------------------------------------------------------------------
// Kernel 1: blocks 0..63: circulant c[n] = sum_m unbind[m]*bind[(m+n)%D].
// blocks 64..317: warmup seg-sums (8-row segs) for 64-row panels 1..127:
//   Sw[p][j][col] = sum_{i=0..7} d^(7-i) x[p*64-32+8j+i][col],  j=0..3
// (batch-start panels produce garbage here; masked by wldz.)
__global__ void k_c(const float* __restrict__ bind,
                    const float* __restrict__ unbind,
                    const float* __restrict__ x,
                    const float* __restrict__ decay,
                    float* __restrict__ c,
                    float* __restrict__ Sw) {
    const int tid = threadIdx.x;
    if (blockIdx.x < 64) {
        __shared__ float sb[Dd];
        __shared__ float su[Dd];
        __shared__ float sp[256];
        for (int j = tid; j < Dd; j += 256) { sb[j] = bind[j]; su[j] = unbind[j]; }
        __syncthreads();
        const int n_loc = tid >> 4;
        const int seg = tid & 15;
        const int n = (int)blockIdx.x * 16 + n_loc;
        float acc = 0.f;
        #pragma unroll 8
        for (int i = 0; i < 64; ++i) {
            const int m = i * 16 + seg;
            acc = fmaf(su[m], sb[(m + n) & (Dd - 1)], acc);
        }
        sp[tid] = acc;
        __syncthreads();
        if (tid < 16) {
            float s = 0.f;
            #pragma unroll
            for (int j = 0; j < 16; ++j) s += sp[tid * 16 + j];
            c[(int)blockIdx.x * 16 + tid] = s;
        }
    } else {
        const int w = (int)blockIdx.x - 64;   // 0..253
        const int p = (w >> 1) + 1;           // panel 1..127
        const int h = w & 1;
        const float dd = sigmoidf_(decay[0]);
        const int col = h * 512 + tid * 2;
        const float* xp = x + (size_t)(p * BM - 32) * Dd + col;
        #pragma unroll
        for (int j = 0; j < 4; ++j) {
            f32x2 sj = (f32x2){0.f, 0.f};
            #pragma unroll
            for (int i = 0; i < 8; ++i)
                sj = dd * sj + *(const f32x2*)&xp[(size_t)(j * 8 + i) * Dd];
            *(f32x2*)&Sw[((size_t)p * 4 + j) * Dd + col] = sj;
        }
    }
}

// ---------------------------------------------------------------------------
// Kernel 2 (fused): out = x + g * (scan_d(x) @ Wt^T), Wt circulant from c.
// R14 = R13 with the ONLY change being __launch_bounds__(256,2) (was (256,4)).
// R13's k=4 capped VGPR at 64 (counter-verified; empirical rule: cap ~
// 512/(2k) for 256-thread blocks -> k=3:84 (R8), k=4:64 (R13)) and spilled
// the scan state to scratch (FETCH 26->57 MB, WRITE 32->70 MB, 77us).
// k=2 -> cap 128 >= natural ~112: no spill, and the hardware still reaches
// 4 blocks/CU (LDS 35.5 KB) x 4 waves = 4 waves/SIMD at ~112 VGPR.
//  * scan: 8 segs x 8 rows; chains = 7 FMAs; carries from 4 predecessor
//    sums C = S[s-1] + d8 S[s-2] + d16 S[s-3] + d24 S[s-4] (trunc d^33).
//  * MFMA: 4 waves x (64 rows x 32-col n-slice); acc 2x f32x16 = 32 regs.
//  * rings, XOR chunk swizzle, C/D layout, 2-deep prefetch: unchanged.
// grid 1024 x 256
__global__ __launch_bounds__(256, 2) void k_fused(
    const float* __restrict__ x,     // [R][D] fp32
    const float* __restrict__ c,     // [D] fp32 circulant kernel
    const float* __restrict__ Sw,    // [128][4][D] warmup seg sums
    const float* __restrict__ decay, // [1]
    const float* __restrict__ gate,  // [1]
    float* __restrict__ out)         // [R][D] fp32
{
    __shared__ __align__(16) __hip_bfloat16 sA[2][BM * BK];  // 2 x 8 KB
    __shared__ __align__(16) __hip_bfloat16 rs[8][RSN];      // 16.1 KB
    __shared__ float sS[12][BK];                             // 3 KB seg sums

    const int tid = threadIdx.x;
    const int wave = tid >> 6;       // 0..3
    const int lane = tid & 63;

    // XCD-grouped mapping: id = xcd + 8*(in_ + 8*gg), bijective over 1024.
    const int id  = blockIdx.x;      // 0..1023
    const int xcd = id & 7;
    const int rr  = id >> 3;         // 0..127
    const int in_ = rr & 7;          // 0..7   col-tile index
    const int gg  = rr >> 3;         // 0..15
    const int im  = xcd * 16 + gg;   // 0..127 row-panel index
    const int tile_m = im * BM;
    const int tile_n = in_ * BN;
    const int pw  = im & 31;         // panel within its batch (2048/64=32)

    const int phase = ((in_ & 1) << 3) | ((gg & 1) << 2);
#define P(T) (((T) + phase) & 15)

    const float dd = sigmoidf_(decay[0]);
    const float d2 = dd * dd, d4 = d2 * d2, d8 = d4 * d4;
    const float d16 = d8 * d8, d24 = d16 * d8;

    // build 8 shifted reversed rings from global c (L2-hot, 4 KB):
    // rs[s][t] = bf16(c[(-(t+s)) mod D])
    #pragma unroll
    for (int s = 0; s < 8; ++s)
        for (int t = tid; t < RSN; t += 256)
            rs[s][t] = __float2bfloat16(c[(-(t + s)) & (Dd - 1)]);

    // ---- scan decomposition: cp = col-pair 0..31, s = seg 0..7 (8 rows) ----
    const int cp = tid & 31;
    const int s  = tid >> 5;         // 0..7
    const bool wldz = (pw == 0);     // first panel in batch: no warmup

    f32x2 vmA[8], vmB[8];            // 2-deep strip prefetch buffers
    f32x2 swA = (f32x2){0.f, 0.f}, swB = (f32x2){0.f, 0.f};

#define LOADSTRIP(V, SWR, ST) do {                                          \
    const int col_ = (ST) * BK + 2 * cp;                                    \
    const float* xp_ = x + (size_t)(tile_m + s * 8) * Dd + col_;            \
    _Pragma("unroll")                                                       \
    for (int i_ = 0; i_ < 8; ++i_)                                          \
        V[i_] = *(const f32x2*)&xp_[(size_t)i_ * Dd];                       \
    if (s >= 4 && !wldz)                                                    \
        SWR = *(const f32x2*)&Sw[((size_t)im * 4 + (s - 4)) * Dd + col_];   \
} while (0)

#define CHAINS(V, SWR) do {                                                 \
    _Pragma("unroll")                                                       \
    for (int i_ = 1; i_ < 8; ++i_) V[i_] = dd * V[i_ - 1] + V[i_];          \
    *(f32x2*)&sS[s][2 * cp] = V[7];                                         \
    if (s >= 4)                                                             \
        *(f32x2*)&sS[8 + (s - 4)][2 * cp] =                                 \
            wldz ? (f32x2){0.f, 0.f} : SWR;                                 \
} while (0)

    // sS[8+j] = Sw[p][j]: j=3 -> rows -8..-1 (S[-1]), j=2 -> S[-2], etc.
    auto loadS = [&](int r) -> f32x2 {
        if (r >= 0) return *(const f32x2*)&sS[r][2 * cp];
        return *(const f32x2*)&sS[12 + r][2 * cp];   // r=-1 -> 11 ... r=-4 -> 8
    };

#define FINISH(V, BB) do {                                                  \
    f32x2 C_ = loadS(s - 1) + d8 * loadS(s - 2)                             \
             + d16 * loadS(s - 3) + d24 * loadS(s - 4);                     \
    float w_ = dd;                                                          \
    _Pragma("unroll")                                                       \
    for (int i_ = 0; i_ < 8; ++i_) {                                        \
        f32x2 h_ = V[i_] + w_ * C_;                                         \
        w_ *= dd;                                                           \
        const int rl_ = s * 8 + i_;                                         \
        const int pos_ = (((2 * cp) >> 3) ^ (rl_ & 7)) * 8 + ((2 * cp) & 7);\
        union { __hip_bfloat16 b; unsigned short u; } ux_, uy_;             \
        ux_.b = __float2bfloat16(h_[0]);                                    \
        uy_.b = __float2bfloat16(h_[1]);                                    \
        ushort2 o_; o_.x = ux_.u; o_.y = uy_.u;                             \
        *(ushort2*)&sA[BB][rl_ * 64 + pos_] = o_;                           \
    }                                                                       \
} while (0)

    // ---- MFMA geometry: 4 waves, each 64 rows x 32-col n-slice ----
    const int wn  = wave * 32;
    const int fm  = lane & 31;
    const int fsw = fm & 7;
    const int fc0 = lane >> 5;
    const int ng0 = tile_n + wn + fm;

    f32x16 acc[2];
    #pragma unroll
    for (int i = 0; i < 2; ++i)
        #pragma unroll
        for (int e = 0; e < 16; ++e)
            acc[i][e] = 0.f;

#define MF(BB, K0) do {                                                     \
    _Pragma("unroll")                                                       \
    for (int kh_ = 0; kh_ < 4; ++kh_) {                                     \
        const int kc_ = kh_ * 2 + fc0;                                      \
        const int ck_ = (K0) + kc_ * 8;                                     \
        bf16x8 af0_ = *(const bf16x8*)                                      \
            &sA[BB][(fm) * 64 + (kc_ ^ fsw) * 8];                           \
        bf16x8 af1_ = *(const bf16x8*)                                      \
            &sA[BB][(32 + fm) * 64 + (kc_ ^ fsw) * 8];                      \
        const int bi0_ = (ck_ - ng0) & (Dd - 1);                            \
        bf16x8 bf0_ = *(const bf16x8*)&rs[bi0_ & 7][bi0_ & ~7];             \
        acc[0] = __builtin_amdgcn_mfma_f32_32x32x16_bf16(                   \
            af0_, bf0_, acc[0], 0, 0, 0);                                   \
        acc[1] = __builtin_amdgcn_mfma_f32_32x32x16_bf16(                   \
            af1_, bf0_, acc[1], 0, 0, 0);                                   \
    }                                                                       \
} while (0)

    // prologue: strips P(0), P(1) issued; strip P(0) -> sA[0]
    LOADSTRIP(vmA, swA, P(0));
    LOADSTRIP(vmB, swB, P(1));
    CHAINS(vmA, swA);
    __syncthreads();              // sS ready (and ring build done)
    FINISH(vmA, 0);
    __syncthreads();              // sA[0] ready

    for (int st = 0; st < NST; st += 2) {
        // even step: MFMA strip P(st) (sA[0]); finish strip P(st+1) -> sA[1]
        if (st + 2 < NST) LOADSTRIP(vmA, swA, P(st + 2));
        MF(0, P(st) * BK);
        CHAINS(vmB, swB);         // strip P(st+1) (loads issued 1 step ago)
        __syncthreads();          // sS visible; sA[0] MFMA reads done
        FINISH(vmB, 1);
        __syncthreads();          // sA[1] ready
        // odd step: MFMA strip P(st+1) (sA[1]); finish P(st+2) -> sA[0]
        if (st + 3 < NST) LOADSTRIP(vmB, swB, P(st + 3));
        MF(1, P(st + 1) * BK);
        if (st + 2 < NST) {
            CHAINS(vmA, swA);     // strip P(st+2)
            __syncthreads();
            FINISH(vmA, 0);
        }
        __syncthreads();
    }

#undef LOADSTRIP
#undef CHAINS
#undef FINISH
#undef MF
#undef P

    // C/D layout (R7-verified): col = lane&31, row = (reg&3)+8*(reg>>2)+4*(lane>>5)
    const float g = gate[0];
    const int colg = tile_n + wn + (lane & 31);
    #pragma unroll
    for (int sm = 0; sm < 2; ++sm) {
        #pragma unroll
        for (int g1 = 0; g1 < 4; ++g1) {
            const int row0 = tile_m + sm * 32 + g1 * 8 + (lane >> 5) * 4;
            #pragma unroll
            for (int r0 = 0; r0 < 4; ++r0) {
                const size_t off = (size_t)(row0 + r0) * Dd + colg;
                out[off] = fmaf(g, acc[sm][g1 * 4 + r0], x[off]);
            }
        }
    }
}

// ---------------------------------------------------------------------------
extern "C" void kernel_launch(void* const* d_in, const int* in_sizes, int n_in,
                              void* d_out, int out_size, void* d_ws, size_t ws_size,
                              hipStream_t stream) {
    const float* x      = (const float*)d_in[0];
    const float* bind   = (const float*)d_in[1];
    const float* unbind = (const float*)d_in[2];
    const float* gate   = (const float*)d_in[3];
    const float* decay  = (const float*)d_in[4];
    float* out = (float*)d_out;

    // workspace: c (4 KB) + Sw (2 MB: 128 panels x 4 x 1024 f32)
    float* c  = (float*)d_ws;
    float* Sw = (float*)((char*)d_ws + 4096);

    k_c    <<<dim3(64 + 2 * (NPAN - 1)), dim3(256), 0, stream>>>(
        bind, unbind, x, decay, c, Sw);
    k_fused<<<dim3(1024), dim3(256), 0, stream>>>(x, c, Sw, decay, gate, out);
}

// Round 15
// 119.799 us; speedup vs baseline: 1.3094x; 1.0901x over previous
//
#include <hip/hip_runtime.h>
#include <hip/hip_bf16.h>

// Problem constants
constexpr int Dd = 1024;           // feature dim
constexpr int Tt = 2048;           // sequence length
constexpr int Bb = 4;              // batch
constexpr int Rr = Bb * Tt;        // rows = 8192
constexpr int RSN = 1032;          // ring entries per shifted copy (1024 + pad)
constexpr int BM  = 128;           // tile rows
constexpr int BN  = 128;           // tile cols
constexpr int BK  = 64;            // K step
constexpr int NST = Dd / BK;       // 16 K-steps

typedef __attribute__((ext_vector_type(2))) float f32x2;
typedef __attribute__((ext_vector_type(16))) float f32x16;
typedef __attribute__((ext_vector_type(8))) short bf16x8;

__device__ __forceinline__ float sigmoidf_(float v) {
    return 1.0f / (1.0f + expf(-v));
}

// ---------------------------------------------------------------------------
// Kernel 1: blocks 0..63: circulant c[n] = sum_m unbind[m]*bind[(m+n)%D].
// blocks 64..189: warmup seg-sums for panels 1..63 (verified R8/R9):
//   Sw[p][0][col] = sum_{i=0..15} d^(15-i) x[p*128-32+i][col]
//   Sw[p][1][col] = sum_{i=0..15} d^(15-i) x[p*128-16+i][col]
__global__ void k_c(const float* __restrict__ bind,
                    const float* __restrict__ unbind,
                    const float* __restrict__ x,
                    const float* __restrict__ decay,
                    float* __restrict__ c,
                    float* __restrict__ Sw) {
    const int tid = threadIdx.x;
    if (blockIdx.x < 64) {
        __shared__ float sb[Dd];
        __shared__ float su[Dd];
        __shared__ float sp[256];
        for (int j = tid; j < Dd; j += 256) { sb[j] = bind[j]; su[j] = unbind[j]; }
        __syncthreads();
        const int n_loc = tid >> 4;
        const int seg = tid & 15;
        const int n = (int)blockIdx.x * 16 + n_loc;
        float acc = 0.f;
        #pragma unroll 8
        for (int i = 0; i < 64; ++i) {
            const int m = i * 16 + seg;
            acc = fmaf(su[m], sb[(m + n) & (Dd - 1)], acc);
        }
        sp[tid] = acc;
        __syncthreads();
        if (tid < 16) {
            float s = 0.f;
            #pragma unroll
            for (int j = 0; j < 16; ++j) s += sp[tid * 16 + j];
            c[(int)blockIdx.x * 16 + tid] = s;
        }
    } else {
        const int w = (int)blockIdx.x - 64;   // 0..125
        const int p = (w >> 1) + 1;           // panel 1..63
        const int h = w & 1;
        const float dd = sigmoidf_(decay[0]);
        const int col = h * 512 + tid * 2;
        const float* xp = x + (size_t)(p * BM - 32) * Dd + col;
        f32x2 s8 = (f32x2){0.f, 0.f}, s9 = (f32x2){0.f, 0.f};
        #pragma unroll
        for (int i = 0; i < 16; ++i)
            s8 = dd * s8 + *(const f32x2*)&xp[(size_t)i * Dd];
        #pragma unroll
        for (int i = 16; i < 32; ++i)
            s9 = dd * s9 + *(const f32x2*)&xp[(size_t)i * Dd];
        *(f32x2*)&Sw[((size_t)p * 2 + 0) * Dd + col] = s8;
        *(f32x2*)&Sw[((size_t)p * 2 + 1) * Dd + col] = s9;
    }
}

// ---------------------------------------------------------------------------
// Kernel 2 (fused): out = x + g * (scan_d(x) @ Wt^T), Wt circulant from c.
// R15 = R9 restored verbatim (session-best: total 120.87, k_fused 44.8-50.1,
// VGPR 100, no spill).  The R10-R14 sweep established:
//  * prefetch depth 2 (R10), phase skew (R10): neutral.
//  * 4 blocks/CU x 2 waves (R12): -20% (less MFMA per barrier-crossing).
//  * 4 blocks/CU x 4 waves at BM=64 (R14): -12%.
//  * launch_bounds k>=3 at 256 threads: VGPR cap 512/(2k) -> spill disaster
//    (R8: 84, R13: 64).
// => the binding constraint is MFMA-work-per-barrier amortizing the serial
// CHAINS->bar->FINISH->bar chain; 128x128/4-wave/2-blocks-per-CU maximizes
// it.  This config is the measured optimum of the structure.
// grid 512 x 256
__global__ __launch_bounds__(256, 2) void k_fused(
    const float* __restrict__ x,     // [R][D] fp32
    const float* __restrict__ c,     // [D] fp32 circulant kernel
    const float* __restrict__ Sw,    // [64][2][D] warmup seg sums
    const float* __restrict__ decay, // [1]
    const float* __restrict__ gate,  // [1]
    float* __restrict__ out)         // [R][D] fp32
{
    __shared__ __align__(16) __hip_bfloat16 sA[2][BM * BK];  // 2 x 16 KB
    __shared__ __align__(16) __hip_bfloat16 rs[8][RSN];      // 16.1 KB
    __shared__ float sS[10][BK];                             // 2.5 KB seg sums

    const int tid = threadIdx.x;
    const int wave = tid >> 6;
    const int lane = tid & 63;

    // XCD-grouped mapping: 8 tile_n consumers of one 128-row x-panel share
    // id&7 (assumed XCD round-robin).
    const int id  = blockIdx.x;      // 0..511
    const int xcd = id & 7;
    const int rr  = id >> 3;         // 0..63
    const int in_ = rr & 7;          // 0..7  col-tile index
    const int gg  = rr >> 3;         // 0..7
    const int im  = xcd * 8 + gg;    // 0..63 row-panel index
    const int tile_m = im * BM;
    const int tile_n = in_ * BN;
    const int pw  = im & 15;         // panel index within its batch row

    const float dd = sigmoidf_(decay[0]);
    const float d2 = dd * dd, d4 = d2 * d2, d8 = d4 * d4;
    const float d16 = d8 * d8, d32 = d16 * d16;

    // build 8 shifted reversed rings straight from global c (L2-hot, 4 KB):
    // rs[s][t] = bf16(c[(-(t+s)) mod D])
    #pragma unroll
    for (int s = 0; s < 8; ++s)
        for (int t = tid; t < RSN; t += 256)
            rs[s][t] = __float2bfloat16(c[(-(t + s)) & (Dd - 1)]);

    // ---- scan decomposition: cp = col-pair 0..31, s = seg 0..7 ----
    const int cp = tid & 31;
    const int s  = tid >> 5;
    const bool wldz = (pw == 0);     // first panel in batch: no warmup

    f32x2 vm[16];                    // strip window / prefix (in place)
    f32x2 sw = (f32x2){0.f, 0.f};    // warmup seg sum (threads s>=6)

    auto loadstrip = [&](int st) {
        const int col = st * BK + 2 * cp;
        const float* xp = x + (size_t)(tile_m + s * 16) * Dd + col;
        #pragma unroll
        for (int i = 0; i < 16; ++i)
            vm[i] = *(const f32x2*)&xp[(size_t)i * Dd];
        if (s >= 6 && !wldz)
            sw = *(const f32x2*)&Sw[((size_t)im * 2 + (s - 6)) * Dd + col];
    };

    auto chains = [&]() {            // local prefix + seg sums -> sS
        #pragma unroll
        for (int i = 1; i < 16; ++i) vm[i] = dd * vm[i - 1] + vm[i];
        *(f32x2*)&sS[s][2 * cp] = vm[15];
        if (s >= 6)
            *(f32x2*)&sS[8 + (s - 6)][2 * cp] =
                wldz ? (f32x2){0.f, 0.f} : sw;
    };

    auto loadS = [&](int r) -> f32x2 {
        if (r >= 0)  return *(const f32x2*)&sS[r][2 * cp];
        if (r == -1) return *(const f32x2*)&sS[9][2 * cp];
        if (r == -2) return *(const f32x2*)&sS[8][2 * cp];
        return (f32x2){0.f, 0.f};
    };

    auto finish = [&](int bb2) {     // carries + bf16 write into sA[bb2]
        f32x2 C = loadS(s - 1) + d16 * loadS(s - 2) + d32 * loadS(s - 3);
        float w = dd;
        #pragma unroll
        for (int i = 0; i < 16; ++i) {
            f32x2 h = vm[i] + w * C;
            w *= dd;
            const int rl = s * 16 + i;
            const int pos = (((2 * cp) >> 3) ^ (rl & 7)) * 8 + (2 * cp & 7);
            ushort2 o;
            union { __hip_bfloat16 b; unsigned short u; } ux, uy;
            ux.b = __float2bfloat16(h[0]);
            uy.b = __float2bfloat16(h[1]);
            o.x = ux.u; o.y = uy.u;
            *(ushort2*)&sA[bb2][rl * 64 + pos] = o;
        }
    };

    // ---- MFMA geometry: 4 waves, 2x2 grid of 64x64 tiles ----
    const int wm  = (wave & 1) * 64;
    const int wn  = (wave >> 1) * 64;
    const int fm  = lane & 31;
    const int fsw = fm & 7;
    const int fc0 = lane >> 5;
    const int ng0 = tile_n + wn + fm;

    f32x16 acc[2][2];
    #pragma unroll
    for (int i = 0; i < 2; ++i)
        #pragma unroll
        for (int j = 0; j < 2; ++j)
            #pragma unroll
            for (int e = 0; e < 16; ++e)
                acc[i][j][e] = 0.f;

    // prologue: strip 0 -> sA[0]
    loadstrip(0);
    chains();
    __syncthreads();
    finish(0);
    __syncthreads();

    for (int st = 0; st < NST; ++st) {
        const int bb = st & 1;
        if (st + 1 < NST) loadstrip(st + 1);   // loads issued before MFMA

        const int k0 = st * BK;
        #pragma unroll
        for (int kh = 0; kh < 4; ++kh) {
            const int kc = kh * 2 + fc0;
            const int ck = k0 + kc * 8;
            bf16x8 af[2], bfr[2];
            #pragma unroll
            for (int sm = 0; sm < 2; ++sm)
                af[sm] = *(const bf16x8*)
                    &sA[bb][(wm + sm * 32 + fm) * 64 + (kc ^ fsw) * 8];
            #pragma unroll
            for (int sn = 0; sn < 2; ++sn) {
                const int bi = (ck - (ng0 + sn * 32)) & (Dd - 1);
                bfr[sn] = *(const bf16x8*)&rs[bi & 7][bi & ~7];
            }
            #pragma unroll
            for (int sm = 0; sm < 2; ++sm)
                #pragma unroll
                for (int sn = 0; sn < 2; ++sn)
                    acc[sm][sn] = __builtin_amdgcn_mfma_f32_32x32x16_bf16(
                        af[sm], bfr[sn], acc[sm][sn], 0, 0, 0);
        }

        if (st + 1 < NST) {
            chains();
            __syncthreads();        // sS visible; sA[bb] MFMA reads done
            finish(bb ^ 1);
        }
        __syncthreads();            // sA[bb^1] ready for next step
    }

    // C/D layout (R7-verified): col = lane&31, row = (reg&3)+8*(reg>>2)+4*(lane>>5)
    const float g = gate[0];
    #pragma unroll
    for (int sm = 0; sm < 2; ++sm) {
        #pragma unroll
        for (int sn = 0; sn < 2; ++sn) {
            const int colg = tile_n + wn + sn * 32 + (lane & 31);
            #pragma unroll
            for (int g1 = 0; g1 < 4; ++g1) {
                const int row0 = tile_m + wm + sm * 32 + g1 * 8 + (lane >> 5) * 4;
                #pragma unroll
                for (int r0 = 0; r0 < 4; ++r0) {
                    const size_t off = (size_t)(row0 + r0) * Dd + colg;
                    out[off] = fmaf(g, acc[sm][sn][g1 * 4 + r0], x[off]);
                }
            }
        }
    }
}

// ---------------------------------------------------------------------------
extern "C" void kernel_launch(void* const* d_in, const int* in_sizes, int n_in,
                              void* d_out, int out_size, void* d_ws, size_t ws_size,
                              hipStream_t stream) {
    const float* x      = (const float*)d_in[0];
    const float* bind   = (const float*)d_in[1];
    const float* unbind = (const float*)d_in[2];
    const float* gate   = (const float*)d_in[3];
    const float* decay  = (const float*)d_in[4];
    float* out = (float*)d_out;

    // workspace: c (4 KB) + Sw (512 KB)
    float* c  = (float*)d_ws;
    float* Sw = (float*)((char*)d_ws + 4096);

    k_c    <<<dim3(190), dim3(256), 0, stream>>>(bind, unbind, x, decay, c, Sw);
    k_fused<<<dim3(512), dim3(256), 0, stream>>>(x, c, Sw, decay, gate, out);
}